// Round 4
// baseline (337.577 us; speedup 1.0000x reference)
//
#include <hip/hip_runtime.h>
#include <cmath>

namespace {

using bf16x8 = __attribute__((ext_vector_type(8))) short;
using f32x4  = __attribute__((ext_vector_type(4))) float;
using f32x4u = __attribute__((ext_vector_type(4), aligned(4))) float;  // 4B-aligned vec load

constexpr int NT = 192;        // 3 waves per block
constexpr int NS = 16;         // samples per block (one MFMA M-tile)
constexpr int LPAD = 31;       // padded position count (Lmax=23 + 8)
constexpr int TILE_BYTES = NS * LPAD * 32 * 2;  // 31744 B

// prepped-weight granule offsets per kernel size k (16B granules): 448*k granules each
constexpr int WOFF1 = 0, WOFF3 = 448, WOFF5 = 1792, WOFF7 = 4032, WOFF9 = 7168;
constexpr int WGRANULES = 11200;   // 448*(1+3+5+7+9)

__device__ __forceinline__ short f2bf(float f) {  // RNE float->bf16
  unsigned u = __float_as_uint(f);
  return (short)((u + 0x7FFFu + ((u >> 16) & 1u)) >> 16);
}

// Granule index for tile[s][q][cq*8..+7]. Bijective: only permutes cq within
// the (s,q) quad. XOR form: with q compile-time, read addr = base + const ops.
__device__ __forceinline__ int gidx(int s, int q, int cq) {
  return (s * 31 + q) * 4 + ((cq ^ (s >> 1) ^ (q >> 1)) & 3);
}

__device__ __forceinline__ bf16x8 ldcol(const char* smem, int s, int cq, int q) {
  return *(const bf16x8*)(smem + (gidx(s, q, cq) << 4));
}

// ---- stage one input tile: x[b0+ss][c][l] (f32) -> tile[ss][l+4][c] (bf16) ----
template<int L>
__device__ __forceinline__ void stage_tile(const float* __restrict__ xi,
                                           char* __restrict__ smem, int tid, int b0) {
  constexpr int L4 = (L + 3) / 4;
  const bf16x8 z = {0, 0, 0, 0, 0, 0, 0, 0};
  // zero the 4+4 SAME-padding columns (branchless taps)
  #pragma unroll
  for (int e0 = 0; e0 < 512; e0 += NT) {
    const int e = e0 + tid;
    if (e < 512) {
      const int q8 = e & 7;
      const int q  = (q8 < 4) ? q8 : (L + q8);
      const int cg = (e >> 3) & 3;
      const int ss = e >> 5;
      *(bf16x8*)(smem + (gidx(ss, q, cg) << 4)) = z;
    }
  }
  // data: item e = (ss, cg, l-quad); float4 loads along l, b128 swizzled writes.
  #pragma unroll
  for (int e0 = 0; e0 < 64 * L4; e0 += NT) {
    const int e = e0 + tid;
    if (e < 64 * L4) {
      const int l4 = e % L4;              // compile-time divisor -> magic mul
      const int rr = e / L4;
      const int cg = rr & 3;
      const int ss = rr >> 2;
      const int l0 = (l4 == L4 - 1) ? (L - 4) : (l4 * 4);  // overlap-back tail
      const float* src = xi + ((size_t)(b0 + ss) * 32 + cg * 8) * L + l0;
      f32x4u v[8];
      #pragma unroll
      for (int j = 0; j < 8; ++j) v[j] = *(const f32x4u*)(src + (size_t)j * L);
      #pragma unroll
      for (int p = 0; p < 4; ++p) {
        bf16x8 pk;
        #pragma unroll
        for (int j = 0; j < 8; ++j) pk[j] = f2bf(v[j][p]);
        *(bf16x8*)(smem + (gidx(ss, l0 + 4 + p, cg) << 4)) = pk;
      }
    }
  }
}

// ---- one wave-role: kernel sizes K1 (and optional nested K2 < K1) ----
template<int K1, int K2, int I, int L>
__device__ __forceinline__ void run_role(
    const char* __restrict__ smem, int s, int cq, int f,
    const bf16x8* __restrict__ wg1, const float* __restrict__ ck1,
    const bf16x8* __restrict__ wg2, const float* __restrict__ ck2,
    const float* __restrict__ dw, f32x4& dvec)
{
  constexpr int KK1 = (K1 - 1) / 2;
  constexpr int KK2 = (K2 > 0) ? (K2 - 1) / 2 : 0;

  // B-fragments: one 16B load each from prepped bf16 weights (L2-resident).
  bf16x8 wf1[K1];
  #pragma unroll
  for (int t = 0; t < K1; ++t)
    wf1[t] = wg1[((I * 16 + f) * 4 + cq) * K1 + t];
  bf16x8 wf2[(K2 > 0) ? K2 : 1];
  if constexpr (K2 > 0) {
    #pragma unroll
    for (int t = 0; t < K2; ++t)
      wf2[t] = wg2[((I * 16 + f) * 4 + cq) * K2 + t];
  }

  const float b1 = ck1[I * 16 + f];
  float b2 = 0.f;
  if constexpr (K2 > 0) b2 = ck2[I * 16 + f];

  f32x4 mx1 = {0.f, 0.f, 0.f, 0.f};   // ReLU folded into max-init 0
  f32x4 mx2 = {0.f, 0.f, 0.f, 0.f};

  // Sliding window invariant: af[(P+t)%K1] holds padded col P + 4 - KK1 + t.
  bf16x8 af[K1];
  #pragma unroll
  for (int j = 0; j < K1; ++j) af[j] = ldcol(smem, s, cq, 4 - KK1 + j);

  auto body = [&](int p, int pi) {
    f32x4 aa = {b1, b1, b1, b1};      // even-tap chain (bias pre-added)
    f32x4 ab = {0.f, 0.f, 0.f, 0.f};  // odd-tap chain (ILP split)
    #pragma unroll
    for (int t = 0; t < K1; ++t) {
      if (t & 1)
        ab = __builtin_amdgcn_mfma_f32_16x16x32_bf16(af[(pi + t) % K1], wf1[t], ab, 0, 0, 0);
      else
        aa = __builtin_amdgcn_mfma_f32_16x16x32_bf16(af[(pi + t) % K1], wf1[t], aa, 0, 0, 0);
    }
    if constexpr (K2 > 0) {
      f32x4 ac = {b2, b2, b2, b2};
      #pragma unroll
      for (int t = 0; t < K2; ++t)
        ac = __builtin_amdgcn_mfma_f32_16x16x32_bf16(af[(pi + (KK1 - KK2) + t) % K1], wf2[t], ac, 0, 0, 0);
      #pragma unroll
      for (int r = 0; r < 4; ++r) mx2[r] = fmaxf(mx2[r], ac[r]);
    }
    #pragma unroll
    for (int r = 0; r < 4; ++r) mx1[r] = fmaxf(mx1[r], aa[r] + ab[r]);
    if (p + pi + 1 < L)                         // folds (all compile-time)
      af[pi] = ldcol(smem, s, cq, p + pi + 5 + KK1);
  };

  #pragma unroll
  for (int p = 0; p + K1 <= L; p += K1) {       // K1-blocked -> static rotation idx
    #pragma unroll
    for (int pi = 0; pi < K1; ++pi) body(p, pi);
  }
  constexpr int PB = (L / K1) * K1;
  #pragma unroll
  for (int pi = 0; pi < K1 - 1; ++pi)           // tail (folds per pi)
    if (PB + pi < L) body(PB, pi);

  {
    const float dv1 = dw[(I * 5 + KK1) * 16 + f];
    #pragma unroll
    for (int r = 0; r < 4; ++r) dvec[r] = fmaf(mx1[r], dv1, dvec[r]);
  }
  if constexpr (K2 > 0) {
    const float dv2 = dw[(I * 5 + KK2) * 16 + f];
    #pragma unroll
    for (int r = 0; r < 4; ++r) dvec[r] = fmaf(mx2[r], dv2, dvec[r]);
  }
}

template<int I, int L>
__device__ __forceinline__ void process_input(
    const float* __restrict__ xi, char* __restrict__ smem,
    int tid, int wid, int lane, int b0,
    const bf16x8* __restrict__ wg,
    const float* __restrict__ c1, const float* __restrict__ c3,
    const float* __restrict__ c5, const float* __restrict__ c7,
    const float* __restrict__ c9, const float* __restrict__ dw,
    f32x4& dvec)
{
  const int s  = lane & 15;   // A-side sample row
  const int cq = lane >> 4;   // k-quadrant (channels cq*8..+7)
  const int f  = lane & 15;   // B-side filter col
  __syncthreads();            // all waves done reading previous tile
  stage_tile<L>(xi, smem, tid, b0);
  __syncthreads();            // tile ready
  if (wid == 0)
    run_role<9, 0, I, L>(smem, s, cq, f, wg + WOFF9, c9, nullptr, nullptr, dw, dvec);
  else if (wid == 1)
    run_role<7, 1, I, L>(smem, s, cq, f, wg + WOFF7, c7, wg + WOFF1, c1, dw, dvec);
  else
    run_role<5, 3, I, L>(smem, s, cq, f, wg + WOFF5, c5, wg + WOFF3, c3, dw, dvec);
}

// ---- weight prep: f32 [7,NF,ED,k] -> bf16x8 fragments, once per launch ----
__global__ void prep_weights(const float* __restrict__ w1, const float* __restrict__ w3,
                             const float* __restrict__ w5, const float* __restrict__ w7,
                             const float* __restrict__ w9, bf16x8* __restrict__ out)
{
  const int g = blockIdx.x * blockDim.x + threadIdx.x;
  if (g >= WGRANULES) return;
  int k, base; const float* w;
  if (g < WOFF3)      { k = 1; base = WOFF1; w = w1; }
  else if (g < WOFF5) { k = 3; base = WOFF3; w = w3; }
  else if (g < WOFF7) { k = 5; base = WOFF5; w = w5; }
  else if (g < WOFF9) { k = 7; base = WOFF7; w = w7; }
  else                { k = 9; base = WOFF9; w = w9; }
  const int r  = g - base;
  const int t  = r % k;
  const int u  = r / k;          // (i*16+f)*4 + cq
  const int fi = u >> 2;
  const int cg = u & 3;
  bf16x8 v;
  #pragma unroll
  for (int j = 0; j < 8; ++j)
    v[j] = f2bf(w[(size_t)(fi * 32 + cg * 8 + j) * k + t]);
  out[g] = v;
}

__global__ __launch_bounds__(NT, 4) void nettcr_mfma(
    const float* __restrict__ x0, const float* __restrict__ x1,
    const float* __restrict__ x2, const float* __restrict__ x3,
    const float* __restrict__ x4, const float* __restrict__ x5,
    const float* __restrict__ x6,
    const float* __restrict__ c1, const float* __restrict__ c3,
    const float* __restrict__ c5, const float* __restrict__ c7,
    const float* __restrict__ c9,
    const float* __restrict__ dw, const float* __restrict__ db,
    const bf16x8* __restrict__ wg,
    float* __restrict__ out)
{
  __shared__ __align__(16) char smem[TILE_BYTES];
  const int tid  = threadIdx.x;
  const int lane = tid & 63;
  const int wid  = tid >> 6;
  const int b0   = blockIdx.x * NS;

  f32x4 dvec = {0.f, 0.f, 0.f, 0.f};
  process_input<0, 12>(x0, smem, tid, wid, lane, b0, wg, c1, c3, c5, c7, c9, dw, dvec);
  process_input<1,  7>(x1, smem, tid, wid, lane, b0, wg, c1, c3, c5, c7, c9, dw, dvec);
  process_input<2,  8>(x2, smem, tid, wid, lane, b0, wg, c1, c3, c5, c7, c9, dw, dvec);
  process_input<3, 22>(x3, smem, tid, wid, lane, b0, wg, c1, c3, c5, c7, c9, dw, dvec);
  process_input<4,  6>(x4, smem, tid, wid, lane, b0, wg, c1, c3, c5, c7, c9, dw, dvec);
  process_input<5,  7>(x5, smem, tid, wid, lane, b0, wg, c1, c3, c5, c7, c9, dw, dvec);
  process_input<6, 23>(x6, smem, tid, wid, lane, b0, wg, c1, c3, c5, c7, c9, dw, dvec);

  // reduce dot partials over 3 waves x 16 filters  (D row = (lane>>4)*4 + r)
  __syncthreads();
  float* red = (float*)smem;
  *(f32x4*)&red[(wid * 64 + lane) * 4] = dvec;
  __syncthreads();
  if (tid < 16) {
    float sum = db[0];
    const int g4 = tid >> 2, r = tid & 3;
    for (int w = 0; w < 3; ++w)
      #pragma unroll
      for (int f2 = 0; f2 < 16; ++f2)
        sum += red[(w * 64 + g4 * 16 + f2) * 4 + r];
    out[b0 + tid] = 1.0f / (1.0f + expf(-sum));
  }
}

} // namespace

extern "C" void kernel_launch(void* const* d_in, const int* in_sizes, int n_in,
                              void* d_out, int out_size, void* d_ws, size_t ws_size,
                              hipStream_t stream) {
  (void)ws_size; (void)out_size;
  const float* xs[7];
  for (int i = 0; i < 7; ++i) xs[i] = (const float*)d_in[i];

  const float* wptr[5] = {nullptr, nullptr, nullptr, nullptr, nullptr};
  const float* cptr[5] = {nullptr, nullptr, nullptr, nullptr, nullptr};
  const float* dw = nullptr;
  const float* db = nullptr;
  int c_seen = 0;
  for (int idx = 7; idx < n_in; ++idx) {
    const int sz = in_sizes[idx];
    const float* p = (const float*)d_in[idx];
    if (sz == 1) { db = p; }
    else if (sz == 16 * 35) { dw = p; }                 // 560
    else if (sz == 7 * 16) { cptr[c_seen++] = p; }      // 112, appear in k order
    else {
      const int k = sz / (7 * 16 * 32);                 // 1,3,5,7,9
      wptr[(k - 1) / 2] = p;
    }
  }

  bf16x8* wg = (bf16x8*)d_ws;   // 11200 granules = 179.2 KB
  hipLaunchKernelGGL(prep_weights, dim3((WGRANULES + 255) / 256), dim3(256), 0, stream,
                     wptr[0], wptr[1], wptr[2], wptr[3], wptr[4], wg);

  float* out = (float*)d_out;
  const int B = 16384;
  dim3 grid(B / NS), block(NT);
  hipLaunchKernelGGL(nettcr_mfma, grid, block, 0, stream,
                     xs[0], xs[1], xs[2], xs[3], xs[4], xs[5], xs[6],
                     cptr[0], cptr[1], cptr[2], cptr[3], cptr[4],
                     dw, db, wg, out);
}

// Round 5
// 208.602 us; speedup vs baseline: 1.6183x; 1.6183x over previous
//
#include <hip/hip_runtime.h>
#include <cmath>

namespace {

using bf16x8 = __attribute__((ext_vector_type(8))) short;
using f32x4  = __attribute__((ext_vector_type(4))) float;
using f32x4u = __attribute__((ext_vector_type(4), aligned(4))) float;  // 4B-aligned vec load

constexpr int NT = 192;        // 3 waves per block
constexpr int NS = 16;         // samples per block (one MFMA M-tile)
constexpr int LPAD = 31;       // padded position count (Lmax=23 + 8)
constexpr int TILE_BYTES = NS * LPAD * 32 * 2;  // 31744 B

// prepped-weight granule offsets per kernel size k (16B granules): 448*k granules each
constexpr int WOFF1 = 0, WOFF3 = 448, WOFF5 = 1792, WOFF7 = 4032, WOFF9 = 7168;
constexpr int WGRANULES = 11200;   // 448*(1+3+5+7+9)

__device__ __forceinline__ short f2bf(float f) {  // RNE float->bf16
  unsigned u = __float_as_uint(f);
  return (short)((u + 0x7FFFu + ((u >> 16) & 1u)) >> 16);
}

// Granule index for tile[s][q][cq*8..+7]. Bijective: only permutes cq within
// the (s,q) quad. XOR form: with q compile-time, read addr = base + const ops.
__device__ __forceinline__ int gidx(int s, int q, int cq) {
  return (s * 31 + q) * 4 + ((cq ^ (s >> 1) ^ (q >> 1)) & 3);
}

__device__ __forceinline__ bf16x8 ldcol(const char* smem, int s, int cq, int q) {
  return *(const bf16x8*)(smem + (gidx(s, q, cq) << 4));
}

// ---- stage one input tile: x[b0+ss][c][l] (f32) -> tile[ss][l+4][c] (bf16) ----
template<int L>
__device__ __forceinline__ void stage_tile(const float* __restrict__ xi,
                                           char* __restrict__ smem, int tid, int b0) {
  constexpr int L4 = (L + 3) / 4;
  const bf16x8 z = {0, 0, 0, 0, 0, 0, 0, 0};
  // zero the 4+4 SAME-padding columns (branchless taps)
  #pragma unroll
  for (int e0 = 0; e0 < 512; e0 += NT) {
    const int e = e0 + tid;
    if (e < 512) {
      const int q8 = e & 7;
      const int q  = (q8 < 4) ? q8 : (L + q8);
      const int cg = (e >> 3) & 3;
      const int ss = e >> 5;
      *(bf16x8*)(smem + (gidx(ss, q, cg) << 4)) = z;
    }
  }
  // data: item e = (ss, cg, l-quad); float4 loads along l, b128 swizzled writes.
  #pragma unroll
  for (int e0 = 0; e0 < 64 * L4; e0 += NT) {
    const int e = e0 + tid;
    if (e < 64 * L4) {
      const int l4 = e % L4;              // compile-time divisor -> magic mul
      const int rr = e / L4;
      const int cg = rr & 3;
      const int ss = rr >> 2;
      const int l0 = (l4 == L4 - 1) ? (L - 4) : (l4 * 4);  // overlap-back tail
      const float* src = xi + ((size_t)(b0 + ss) * 32 + cg * 8) * L + l0;
      f32x4u v[8];
      #pragma unroll
      for (int j = 0; j < 8; ++j) v[j] = *(const f32x4u*)(src + (size_t)j * L);
      #pragma unroll
      for (int p = 0; p < 4; ++p) {
        bf16x8 pk;
        #pragma unroll
        for (int j = 0; j < 8; ++j) pk[j] = f2bf(v[j][p]);
        *(bf16x8*)(smem + (gidx(ss, l0 + 4 + p, cg) << 4)) = pk;
      }
    }
  }
}

// ---- one wave-role: kernel sizes K1 (and optional nested K2 < K1) ----
template<int K1, int K2, int I, int L>
__device__ __forceinline__ void run_role(
    const char* __restrict__ smem, int s, int cq, int f,
    const bf16x8* __restrict__ wg1, const float* __restrict__ ck1,
    const bf16x8* __restrict__ wg2, const float* __restrict__ ck2,
    const float* __restrict__ dw, f32x4& dvec)
{
  constexpr int KK1 = (K1 - 1) / 2;
  constexpr int KK2 = (K2 > 0) ? (K2 - 1) / 2 : 0;

  // B-fragments: one 16B load each from prepped bf16 weights (L2-resident).
  bf16x8 wf1[K1];
  #pragma unroll
  for (int t = 0; t < K1; ++t)
    wf1[t] = wg1[((I * 16 + f) * 4 + cq) * K1 + t];
  bf16x8 wf2[(K2 > 0) ? K2 : 1];
  if constexpr (K2 > 0) {
    #pragma unroll
    for (int t = 0; t < K2; ++t)
      wf2[t] = wg2[((I * 16 + f) * 4 + cq) * K2 + t];
  }

  const float b1 = ck1[I * 16 + f];
  float b2 = 0.f;
  if constexpr (K2 > 0) b2 = ck2[I * 16 + f];

  f32x4 mx1 = {0.f, 0.f, 0.f, 0.f};   // ReLU folded into max-init 0
  f32x4 mx2 = {0.f, 0.f, 0.f, 0.f};

  // Sliding window invariant: af[(P+t)%K1] holds padded col P + 4 - KK1 + t.
  bf16x8 af[K1];
  #pragma unroll
  for (int j = 0; j < K1; ++j) af[j] = ldcol(smem, s, cq, 4 - KK1 + j);

  auto body = [&](int p, int pi) {
    f32x4 aa = {b1, b1, b1, b1};      // even-tap chain (bias pre-added)
    f32x4 ab = {0.f, 0.f, 0.f, 0.f};  // odd-tap chain (ILP split)
    #pragma unroll
    for (int t = 0; t < K1; ++t) {
      if (t & 1)
        ab = __builtin_amdgcn_mfma_f32_16x16x32_bf16(af[(pi + t) % K1], wf1[t], ab, 0, 0, 0);
      else
        aa = __builtin_amdgcn_mfma_f32_16x16x32_bf16(af[(pi + t) % K1], wf1[t], aa, 0, 0, 0);
    }
    if constexpr (K2 > 0) {
      f32x4 ac = {b2, b2, b2, b2};
      #pragma unroll
      for (int t = 0; t < K2; ++t)
        ac = __builtin_amdgcn_mfma_f32_16x16x32_bf16(af[(pi + (KK1 - KK2) + t) % K1], wf2[t], ac, 0, 0, 0);
      #pragma unroll
      for (int r = 0; r < 4; ++r) mx2[r] = fmaxf(mx2[r], ac[r]);
    }
    #pragma unroll
    for (int r = 0; r < 4; ++r) mx1[r] = fmaxf(mx1[r], aa[r] + ab[r]);
    if (p + pi + 1 < L)                         // folds (all compile-time)
      af[pi] = ldcol(smem, s, cq, p + pi + 5 + KK1);
  };

  #pragma unroll
  for (int p = 0; p + K1 <= L; p += K1) {       // K1-blocked -> static rotation idx
    #pragma unroll
    for (int pi = 0; pi < K1; ++pi) body(p, pi);
  }
  constexpr int PB = (L / K1) * K1;
  #pragma unroll
  for (int pi = 0; pi < K1 - 1; ++pi)           // tail (folds per pi)
    if (PB + pi < L) body(PB, pi);

  {
    const float dv1 = dw[(I * 5 + KK1) * 16 + f];
    #pragma unroll
    for (int r = 0; r < 4; ++r) dvec[r] = fmaf(mx1[r], dv1, dvec[r]);
  }
  if constexpr (K2 > 0) {
    const float dv2 = dw[(I * 5 + KK2) * 16 + f];
    #pragma unroll
    for (int r = 0; r < 4; ++r) dvec[r] = fmaf(mx2[r], dv2, dvec[r]);
  }
}

template<int I, int L>
__device__ __forceinline__ void process_input(
    const float* __restrict__ xi, char* __restrict__ smem,
    int tid, int wid, int lane, int b0,
    const bf16x8* __restrict__ wg,
    const float* __restrict__ c1, const float* __restrict__ c3,
    const float* __restrict__ c5, const float* __restrict__ c7,
    const float* __restrict__ c9, const float* __restrict__ dw,
    f32x4& dvec)
{
  const int s  = lane & 15;   // A-side sample row
  const int cq = lane >> 4;   // k-quadrant (channels cq*8..+7)
  const int f  = lane & 15;   // B-side filter col
  __syncthreads();            // all waves done reading previous tile
  stage_tile<L>(xi, smem, tid, b0);
  __syncthreads();            // tile ready
  if (wid == 0)
    run_role<9, 0, I, L>(smem, s, cq, f, wg + WOFF9, c9, nullptr, nullptr, dw, dvec);
  else if (wid == 1)
    run_role<7, 1, I, L>(smem, s, cq, f, wg + WOFF7, c7, wg + WOFF1, c1, dw, dvec);
  else
    run_role<5, 3, I, L>(smem, s, cq, f, wg + WOFF5, c5, wg + WOFF3, c3, dw, dvec);
}

// ---- weight prep: f32 [7,NF,ED,k] -> bf16x8 fragments, once per launch ----
__global__ void prep_weights(const float* __restrict__ w1, const float* __restrict__ w3,
                             const float* __restrict__ w5, const float* __restrict__ w7,
                             const float* __restrict__ w9, bf16x8* __restrict__ out)
{
  const int g = blockIdx.x * blockDim.x + threadIdx.x;
  if (g >= WGRANULES) return;
  int k, base; const float* w;
  if (g < WOFF3)      { k = 1; base = WOFF1; w = w1; }
  else if (g < WOFF5) { k = 3; base = WOFF3; w = w3; }
  else if (g < WOFF7) { k = 5; base = WOFF5; w = w5; }
  else if (g < WOFF9) { k = 7; base = WOFF7; w = w7; }
  else                { k = 9; base = WOFF9; w = w9; }
  const int r  = g - base;
  const int t  = r % k;
  const int u  = r / k;          // (i*16+f)*4 + cq
  const int fi = u >> 2;
  const int cg = u & 3;
  bf16x8 v;
  #pragma unroll
  for (int j = 0; j < 8; ++j)
    v[j] = f2bf(w[(size_t)(fi * 32 + cg * 8 + j) * k + t]);
  out[g] = v;
}

__global__ __launch_bounds__(NT, 3) void nettcr_mfma(
    const float* __restrict__ x0, const float* __restrict__ x1,
    const float* __restrict__ x2, const float* __restrict__ x3,
    const float* __restrict__ x4, const float* __restrict__ x5,
    const float* __restrict__ x6,
    const float* __restrict__ c1, const float* __restrict__ c3,
    const float* __restrict__ c5, const float* __restrict__ c7,
    const float* __restrict__ c9,
    const float* __restrict__ dw, const float* __restrict__ db,
    const bf16x8* __restrict__ wg,
    float* __restrict__ out)
{
  __shared__ __align__(16) char smem[TILE_BYTES];
  const int tid  = threadIdx.x;
  const int lane = tid & 63;
  const int wid  = tid >> 6;
  const int b0   = blockIdx.x * NS;

  f32x4 dvec = {0.f, 0.f, 0.f, 0.f};
  process_input<0, 12>(x0, smem, tid, wid, lane, b0, wg, c1, c3, c5, c7, c9, dw, dvec);
  process_input<1,  7>(x1, smem, tid, wid, lane, b0, wg, c1, c3, c5, c7, c9, dw, dvec);
  process_input<2,  8>(x2, smem, tid, wid, lane, b0, wg, c1, c3, c5, c7, c9, dw, dvec);
  process_input<3, 22>(x3, smem, tid, wid, lane, b0, wg, c1, c3, c5, c7, c9, dw, dvec);
  process_input<4,  6>(x4, smem, tid, wid, lane, b0, wg, c1, c3, c5, c7, c9, dw, dvec);
  process_input<5,  7>(x5, smem, tid, wid, lane, b0, wg, c1, c3, c5, c7, c9, dw, dvec);
  process_input<6, 23>(x6, smem, tid, wid, lane, b0, wg, c1, c3, c5, c7, c9, dw, dvec);

  // reduce dot partials over 3 waves x 16 filters  (D row = (lane>>4)*4 + r)
  __syncthreads();
  float* red = (float*)smem;
  *(f32x4*)&red[(wid * 64 + lane) * 4] = dvec;
  __syncthreads();
  if (tid < 16) {
    float sum = db[0];
    const int g4 = tid >> 2, r = tid & 3;
    for (int w = 0; w < 3; ++w)
      #pragma unroll
      for (int f2 = 0; f2 < 16; ++f2)
        sum += red[(w * 64 + g4 * 16 + f2) * 4 + r];
    out[b0 + tid] = 1.0f / (1.0f + expf(-sum));
  }
}

} // namespace

extern "C" void kernel_launch(void* const* d_in, const int* in_sizes, int n_in,
                              void* d_out, int out_size, void* d_ws, size_t ws_size,
                              hipStream_t stream) {
  (void)ws_size; (void)out_size;
  const float* xs[7];
  for (int i = 0; i < 7; ++i) xs[i] = (const float*)d_in[i];

  const float* wptr[5] = {nullptr, nullptr, nullptr, nullptr, nullptr};
  const float* cptr[5] = {nullptr, nullptr, nullptr, nullptr, nullptr};
  const float* dw = nullptr;
  const float* db = nullptr;
  int c_seen = 0;
  for (int idx = 7; idx < n_in; ++idx) {
    const int sz = in_sizes[idx];
    const float* p = (const float*)d_in[idx];
    if (sz == 1) { db = p; }
    else if (sz == 16 * 35) { dw = p; }                 // 560
    else if (sz == 7 * 16) { cptr[c_seen++] = p; }      // 112, appear in k order
    else {
      const int k = sz / (7 * 16 * 32);                 // 1,3,5,7,9
      wptr[(k - 1) / 2] = p;
    }
  }

  bf16x8* wg = (bf16x8*)d_ws;   // 11200 granules = 179.2 KB
  hipLaunchKernelGGL(prep_weights, dim3((WGRANULES + 255) / 256), dim3(256), 0, stream,
                     wptr[0], wptr[1], wptr[2], wptr[3], wptr[4], wg);

  float* out = (float*)d_out;
  const int B = 16384;
  dim3 grid(B / NS), block(NT);
  hipLaunchKernelGGL(nettcr_mfma, grid, block, 0, stream,
                     xs[0], xs[1], xs[2], xs[3], xs[4], xs[5], xs[6],
                     cptr[0], cptr[1], cptr[2], cptr[3], cptr[4],
                     dw, db, wg, out);
}